// Round 1
// baseline (1048.237 us; speedup 1.0000x reference)
//
#include <hip/hip_runtime.h>

// Resample2d: B=8, C=64, H=256, W=256, kernel_size=4, dilation=1, sigma=5.
// Weights are channel-independent and separable in x/y fractional offsets:
//   wy_i = exp(-(i - frac_y)^2 / (2 s^2)),  wx_j = exp(-(j - frac_x)^2 / (2 s^2))
//   wsum = (sum_i wy_i) * (sum_j wx_j)
// So: per spatial location compute 8 exps, fold 1/wsum into 16 tap weights,
// precompute 16 flat offsets, then loop 64 channels reusing them.
// Block = one image row (b,h) -> b,h block-uniform; w = threadIdx.x -> stores
// coalesced, gather loads use uniform SGPR base + per-lane offset.

constexpr int Bc = 8, Cc = 64, Hc = 256, Wc = 256;
constexpr int HWc = Hc * Wc;

__global__ __launch_bounds__(256) void resample2d_kernel(
    const float* __restrict__ img, const float* __restrict__ flow,
    float* __restrict__ out) {
  const int b = blockIdx.x >> 8;       // 256 rows per image
  const int h = blockIdx.x & 255;
  const int w = threadIdx.x;           // W == 256 == blockDim.x
  const int hw = (h << 8) | w;

  const float inv2s2 = 1.0f / (2.0f * 5.0f * 5.0f);

  const float* flowb = flow + (size_t)b * 2 * HWc;
  const float fx = flowb[hw];
  const float fy = flowb[HWc + hw];
  const float xf = (float)w + fx;
  const float yf = (float)h + fy;
  const float x0 = floorf(xf);
  const float y0 = floorf(yf);

  float wx[4], wy[4];
  int xi[4], yi[4];
  float sx = 0.f, sy = 0.f;
#pragma unroll
  for (int j = 0; j < 4; ++j) {
    const float xs = x0 + (float)j;      // dilation == 1
    const float dx = xs - xf;
    wx[j] = __expf(-dx * dx * inv2s2);
    sx += wx[j];
    xi[j] = min(max((int)xs, 0), Wc - 1);

    const float ys = y0 + (float)j;
    const float dy = ys - yf;
    wy[j] = __expf(-dy * dy * inv2s2);
    sy += wy[j];
    yi[j] = min(max((int)ys, 0), Hc - 1);
  }
  const float inv_wsum = 1.0f / (sx * sy + 1e-8f);

  int off[16];
  float wgt[16];
#pragma unroll
  for (int i = 0; i < 4; ++i) {
#pragma unroll
    for (int j = 0; j < 4; ++j) {
      off[i * 4 + j] = yi[i] * Wc + xi[j];
      wgt[i * 4 + j] = wy[i] * wx[j] * inv_wsum;
    }
  }

  const float* imgb = img + (size_t)b * Cc * HWc;
  float* outp = out + (size_t)b * Cc * HWc + hw;
#pragma unroll 2
  for (int c = 0; c < Cc; ++c) {
    const float* p = imgb + (size_t)c * HWc;
    float acc = 0.f;
#pragma unroll
    for (int k = 0; k < 16; ++k) acc = fmaf(p[off[k]], wgt[k], acc);
    outp[(size_t)c * HWc] = acc;
  }
}

extern "C" void kernel_launch(void* const* d_in, const int* in_sizes, int n_in,
                              void* d_out, int out_size, void* d_ws, size_t ws_size,
                              hipStream_t stream) {
  const float* img = (const float*)d_in[0];   // (8,64,256,256) fp32
  const float* flow = (const float*)d_in[1];  // (8,2,256,256) fp32
  float* out = (float*)d_out;                 // (8,64,256,256) fp32

  dim3 grid(Bc * Hc);   // 2048 blocks: one per (b, h) row
  dim3 block(Wc);       // 256 threads: one per w
  hipLaunchKernelGGL(resample2d_kernel, grid, block, 0, stream, img, flow, out);
}

// Round 2
// 811.414 us; speedup vs baseline: 1.2919x; 1.2919x over previous
//
#include <hip/hip_runtime.h>

// Resample2d: B=8, C=64, H=256, W=256, ks=4, dilation=1, sigma=5.
// R1 finding: TA/address-divergence bound (70 cyc per wave-gather, all pipes
// idle). R2: collapse the 4 consecutive x-taps of each row into ONE unaligned
// 16B load (global_load_dwordx4) -> 4 row-gathers/channel instead of 16 scalar
// gathers. Border lanes (x-clamp active) take a scalar fallback; only the two
// edge waves of each row ever hit it (P(|fx|>64) ~ 0).

constexpr int Bc = 8, Cc = 64, Hc = 256, Wc = 256;
constexpr int HWc = Hc * Wc;

typedef float f4 __attribute__((ext_vector_type(4)));

__device__ __forceinline__ f4 load16_u(const float* p) {
  f4 r;
  __builtin_memcpy(&r, p, 16);  // align-4 16B load -> global_load_dwordx4
  return r;
}

__global__ __launch_bounds__(256) void resample2d_kernel(
    const float* __restrict__ img, const float* __restrict__ flow,
    float* __restrict__ out) {
  const int b = blockIdx.x >> 8;       // 256 rows per image
  const int h = blockIdx.x & 255;
  const int w = threadIdx.x;           // W == 256 == blockDim.x
  const int hw = (h << 8) | w;

  const float inv2s2 = 1.0f / 50.0f;   // 1/(2*sigma^2), sigma=5

  const float* flowb = flow + (size_t)b * 2 * HWc;
  const float fx = flowb[hw];
  const float fy = flowb[HWc + hw];
  const float xf = (float)w + fx;
  const float yf = (float)h + fy;
  const float x0 = floorf(xf);
  const float y0 = floorf(yf);
  const int x0i = (int)x0;

  float wx[4], wy[4];
  int yi[4], xi[4];
  float sx = 0.f, sy = 0.f;
#pragma unroll
  for (int j = 0; j < 4; ++j) {
    const float dx = x0 + (float)j - xf;
    wx[j] = __expf(-dx * dx * inv2s2);
    sx += wx[j];
    xi[j] = min(max(x0i + j, 0), Wc - 1);

    const float dy = y0 + (float)j - yf;
    wy[j] = __expf(-dy * dy * inv2s2);
    sy += wy[j];
    yi[j] = min(max((int)y0 + j, 0), Hc - 1);
  }
  const float inv_wsum = 1.0f / (sx * sy + 1e-8f);

  // Fold 1/wsum into the y-weights; row byte-offsets.
  int rowoff[4];
#pragma unroll
  for (int i = 0; i < 4; ++i) {
    wy[i] *= inv_wsum;
    rowoff[i] = yi[i] * Wc;
  }

  const bool interior = (x0i >= 0) & (x0i <= Wc - 4);

  const float* imgb = img + (size_t)b * Cc * HWc;
  float* outp = out + (size_t)b * Cc * HWc + hw;

  if (interior) {
    // Fast path: 4 unaligned 16B row loads per channel.
#pragma unroll 4
    for (int c = 0; c < Cc; ++c) {
      const float* p = imgb + (size_t)c * HWc + x0i;
      float acc = 0.f;
#pragma unroll
      for (int i = 0; i < 4; ++i) {
        const f4 v = load16_u(p + rowoff[i]);
        float r = v.x * wx[0];
        r = fmaf(v.y, wx[1], r);
        r = fmaf(v.z, wx[2], r);
        r = fmaf(v.w, wx[3], r);
        acc = fmaf(r, wy[i], acc);
      }
      outp[(size_t)c * HWc] = acc;
    }
  } else {
    // Border path: 16 scalar clamped gathers per channel.
#pragma unroll 2
    for (int c = 0; c < Cc; ++c) {
      const float* p = imgb + (size_t)c * HWc;
      float acc = 0.f;
#pragma unroll
      for (int i = 0; i < 4; ++i) {
        float r = 0.f;
#pragma unroll
        for (int j = 0; j < 4; ++j) r = fmaf(p[rowoff[i] + xi[j]], wx[j], r);
        acc = fmaf(r, wy[i], acc);
      }
      outp[(size_t)c * HWc] = acc;
    }
  }
}

extern "C" void kernel_launch(void* const* d_in, const int* in_sizes, int n_in,
                              void* d_out, int out_size, void* d_ws, size_t ws_size,
                              hipStream_t stream) {
  const float* img = (const float*)d_in[0];   // (8,64,256,256) fp32
  const float* flow = (const float*)d_in[1];  // (8,2,256,256) fp32
  float* out = (float*)d_out;                 // (8,64,256,256) fp32

  dim3 grid(Bc * Hc);   // one block per (b, h) row
  dim3 block(Wc);
  hipLaunchKernelGGL(resample2d_kernel, grid, block, 0, stream, img, flow, out);
}